// Round 7
// baseline (164.531 us; speedup 1.0000x reference)
//
#include <hip/hip_runtime.h>
#include <hip/hip_bf16.h>

#define NE 32
#define MM 1024
#define KK 512
#define NN 512
#define BM 128
#define BN 128
#define BK 64          // fp32 k-slab staged via global_load_lds; 8 slabs
#define NS (KK / BK)

typedef __attribute__((ext_vector_type(8))) short bf16x8;
typedef __attribute__((ext_vector_type(4))) float floatx4;

__device__ __forceinline__ short f2bf(float f) {
  union { __hip_bfloat16 b; short s; } u;
  u.b = __float2bfloat16(f);   // RNE
  return u.s;
}

// Async 16B/lane DMA: global (per-lane addr) -> LDS (wave-uniform base + lane*16B).
// One issue covers 64 lanes * 16 B = 1024 B = 256 floats of LDS.
__device__ __forceinline__ void dma16(const float* g, float* l) {
  __builtin_amdgcn_global_load_lds(
      (const __attribute__((address_space(1))) unsigned int*)g,
      (__attribute__((address_space(3))) unsigned int*)l, 16, 0, 0);
}

// One item per block. XCD-aware: b -> xcd b&7, slot b>>3; XCD x owns experts
// {x,x+8,x+16,x+24}. Per-XCD items = 32 + 3*sum(vt) <= 128 slots, structurally.
// GEMM tiles first, zero stripes last.
extern "C" __global__ __launch_bounds__(256, 2)
void expert_gemm(const float* __restrict__ A, const float* __restrict__ B,
                 const int* __restrict__ cnts, float* __restrict__ C)
{
  const int xcd  = blockIdx.x & 7;
  const int slot = blockIdx.x >> 3;
  const int tid  = threadIdx.x;

  int e = -1, mt = 0, nt = 0;
  int acc = 0;
#pragma unroll
  for (int g = 0; g < 4; ++g) {
    int ee = xcd + (g << 3);
    int vt = (cnts[ee] + BM - 1) >> 7;
    int c4 = vt << 2;
    if (e < 0 && slot < acc + c4) { int r = slot - acc; e = ee; mt = r >> 2; nt = r & 3; }
    acc += c4;
  }
  if (e < 0) {
    int z = slot - acc, a2 = 0;
#pragma unroll
    for (int g = 0; g < 4; ++g) {
      int ee = xcd + (g << 3);
      int vt = (cnts[ee] + BM - 1) >> 7;
      int c = 8 - vt;
      if (e < 0 && z < a2 + c) { e = ee; mt = vt + (z - a2); }
      a2 += c;
    }
    if (e < 0) return;
    // zero-fill a 128x512 stripe (harness poisons d_out to 0xAA each launch)
    float* Ce = C + ((size_t)e * MM + mt * BM) * NN;
    float4 zf = make_float4(0.f, 0.f, 0.f, 0.f);
#pragma unroll
    for (int i = 0; i < 64; ++i) {
      int fidx = i * 256 + tid;
      int r = fidx >> 7, c = (fidx & 127) << 2;
      *(float4*)(Ce + (size_t)r * NN + c) = zf;
    }
    return;
  }

  // ---- GEMM tile: C[e][m0:m0+128][n0:n0+128] = A[e] @ B[e]^T ----
  const int m0 = mt * BM, n0 = nt * BN;
  const int cnt = cnts[e];
  const float* Ae = A + ((size_t)e * MM + m0) * KK;
  const float* Be = B + ((size_t)e * NN + n0) * KK;
  float* Ce = C + ((size_t)e * MM + m0) * NN + n0;

  // LDS: fp32 slab, physical 16B-chunk index p = row*16 + pk (chunk at float
  // offset p*4). DMA issue i writes chunks p = i*64 + lane (base = i*256
  // floats): row = 4i + (lane>>4), pk = lane&15. Swizzle on the GATHER side:
  // logical kb lives at pk = kb ^ (row&15), so lane fetches kb = (lane&15) ^
  // (row&15) -> global segments remain contiguous 256 B runs (lanes permuted
  // within); read-side b128 conflict-free.
  __shared__ __align__(16) float sA[BM * BK];  // 32 KB
  __shared__ __align__(16) float sB[BN * BK];  // 32 KB

  const int wave = tid >> 6, lane = tid & 63;
  const int wm = (wave >> 1) * 64, wn = (wave & 1) * 64;
  const int fr = lane & 15, kh = lane >> 4;
  const int ld = lane >> 4;       // lane's row-within-issue (0..3)
  const int lk = lane & 15;       // lane's pk (0..15)

  floatx4 acc4[4][4] = {};

#pragma unroll 1
  for (int s = 0; s < NS; ++s) {
    const int kt = s * BK;
    // DMA this slab: 32 issues for A + 32 for B, split 8+8 per wave.
#pragma unroll
    for (int q = 0; q < 8; ++q) {
      int i   = wave * 8 + q;
      int row = 4 * i + ld;
      int kb  = lk ^ (row & 15);
      dma16(Ae + (size_t)row * KK + kt + kb * 4, sA + i * 256);  // i*256 floats = i*1024 B
      dma16(Be + (size_t)row * KK + kt + kb * 4, sB + i * 256);
    }
    __syncthreads();   // vmcnt(0) drain: 64 KB burst completes as one deep pipeline

    // compute: 2 MFMA k-windows of 32 per slab, convert fp32->bf16 on read
#pragma unroll
    for (int ks = 0; ks < 2; ++ks) {
      bf16x8 af[4], bfv[4];
#pragma unroll
      for (int i = 0; i < 4; ++i) {
        int rA  = wm + (i << 4) + fr;
        int kb0 = ks * 8 + kh * 2;
        float4 f0 = *(const float4*)(sA + ((rA << 4) + (kb0 ^ (rA & 15))) * 4);
        float4 f1 = *(const float4*)(sA + ((rA << 4) + ((kb0 + 1) ^ (rA & 15))) * 4);
        af[i] = (bf16x8){ f2bf(f0.x), f2bf(f0.y), f2bf(f0.z), f2bf(f0.w),
                          f2bf(f1.x), f2bf(f1.y), f2bf(f1.z), f2bf(f1.w) };
        int rB  = wn + (i << 4) + fr;
        float4 g0 = *(const float4*)(sB + ((rB << 4) + (kb0 ^ (rB & 15))) * 4);
        float4 g1 = *(const float4*)(sB + ((rB << 4) + ((kb0 + 1) ^ (rB & 15))) * 4);
        bfv[i] = (bf16x8){ f2bf(g0.x), f2bf(g0.y), f2bf(g0.z), f2bf(g0.w),
                           f2bf(g1.x), f2bf(g1.y), f2bf(g1.z), f2bf(g1.w) };
      }
#pragma unroll
      for (int i = 0; i < 4; ++i)
#pragma unroll
        for (int j = 0; j < 4; ++j)
          acc4[i][j] = __builtin_amdgcn_mfma_f32_16x16x32_bf16(af[i], bfv[j], acc4[i][j], 0, 0, 0);
    }
    __syncthreads();   // all reads done before next slab's DMA overwrites
  }

  // epilogue: C/D layout col=lane&15, row=(lane>>4)*4+reg (m89/m91-verified)
  const int rb_ = (lane >> 4) * 4;
#pragma unroll
  for (int i = 0; i < 4; ++i) {
#pragma unroll
    for (int r = 0; r < 4; ++r) {
      int row = wm + i * 16 + rb_ + r;
      bool valid = (m0 + row) < cnt;
#pragma unroll
      for (int j = 0; j < 4; ++j) {
        int col = wn + j * 16 + fr;
        Ce[(size_t)row * NN + col] = valid ? acc4[i][j][r] : 0.0f;
      }
    }
  }
}

extern "C" void kernel_launch(void* const* d_in, const int* in_sizes, int n_in,
                              void* d_out, int out_size, void* d_ws, size_t ws_size,
                              hipStream_t stream) {
  const float* A    = (const float*)d_in[0];
  const float* B    = (const float*)d_in[1];
  const int*   cnts = (const int*)d_in[2];
  float*       C    = (float*)d_out;

  hipLaunchKernelGGL(expert_gemm, dim3(1024), dim3(256), 0, stream, A, B, cnts, C);
}